// Round 3
// baseline (375.121 us; speedup 1.0000x reference)
//
#include <hip/hip_runtime.h>
#include <hip/hip_bf16.h>

// B=4, S=2048, E=1024, H=16, D=64, WIN=512.
// out = ( swa_alibi( split_heads(x @ w_in^T) ) merged ) @ w_out^T
//
// k0: detect input dtype (f32 vs bf16) -> flag; cvt inputs to bf16 ws (no-op if bf16)
// k1: qkv = x @ w_in^T          (gemm_bt, m97-style global_load_lds staging)
// k2: o   = sliding-window attn (S^T orientation: vectorized P transform, no V-scatter)
// k3: out = o @ w_out^T

typedef __bf16 bf16x8 __attribute__((ext_vector_type(8)));
typedef float f32x4 __attribute__((ext_vector_type(4)));

__device__ __forceinline__ f32x4 mfma16(bf16x8 a, bf16x8 b, f32x4 c) {
    return __builtin_amdgcn_mfma_f32_16x16x32_bf16(a, b, c, 0, 0, 0);
}

// CK-style addrspace casts via integer round-trip (LDS generic ptr low 32 bits = offset).
__device__ __forceinline__ void gload_lds16(const void* g, void* l) {
    __builtin_amdgcn_global_load_lds(
        (const __attribute__((address_space(1))) unsigned int*)(unsigned long long)g,
        (__attribute__((address_space(3))) unsigned int*)(unsigned int)(unsigned long long)l,
        16, 0, 0);
}

__device__ __forceinline__ unsigned pkbf(float a, float b) {
    unsigned short ua = __builtin_bit_cast(unsigned short, (__bf16)a);
    unsigned short ub = __builtin_bit_cast(unsigned short, (__bf16)b);
    return (unsigned)ua | ((unsigned)ub << 16);
}

__global__ void init_flag(int* flag) { *flag = 0; }

// f32 data read as bf16 halfwords shows huge exponents in odd halves (p~0.45/scan).
__global__ void detect_f32(const unsigned short* __restrict__ w, int n, int* flag) {
    int i = blockIdx.x * blockDim.x + threadIdx.x;
    int hit = 0;
    for (; i < n; i += gridDim.x * blockDim.x) {
        int e = (w[i] >> 7) & 0xFF;
        if (e >= 0x8D) hit = 1;
    }
    unsigned long long m = __ballot(hit);
    if (m != 0 && (threadIdx.x & 63) == 0) atomicOr(flag, 1);
}

// Only does work when flag==1 (inputs are f32): converts to bf16.
__global__ void cvt_bf16(const void* __restrict__ src, __bf16* __restrict__ dst,
                         int n, const int* __restrict__ flag) {
    if (*flag == 0) return;
    const float* s = (const float*)src;
    int i = blockIdx.x * blockDim.x + threadIdx.x;
    for (; i < n; i += gridDim.x * blockDim.x) dst[i] = (__bf16)s[i];
}

// C[M,N] = A[M,K] @ Bt[N,K]^T. m97 pattern: 128x128 tile, BK=32, unpadded LDS,
// global_load_lds width-16 staging. A operand selected on-device by flag
// (raw input may be f32 -> use converted copy).
__global__ __launch_bounds__(256, 3) void gemm_bt(
        const void* __restrict__ Araw, const __bf16* __restrict__ Acvt,
        const void* __restrict__ Braw, const __bf16* __restrict__ Bcvt,
        __bf16* __restrict__ Cb, float* __restrict__ Cf,
        const int* __restrict__ flagp, int M, int N, int K) {
    __shared__ __align__(16) __bf16 As[128 * 32];
    __shared__ __align__(16) __bf16 Bs[128 * 32];

    const int t = threadIdx.x;
    const int lane = t & 63;
    const int w = t >> 6;
    const int wr = w >> 1, wc = w & 1;
    const int q4 = lane >> 4, l16 = lane & 15;
    const int m0 = blockIdx.y * 128, n0 = blockIdx.x * 128;
    const bool isf32 = (*flagp != 0);
    const __bf16* A = isf32 ? Acvt : (const __bf16*)Araw;
    const __bf16* Bt = isf32 ? Bcvt : (const __bf16*)Braw;

    f32x4 acc[4][4] = {};

    const int srow = lane >> 2, scol = (lane & 3) * 8;  // per-lane staging coords

    for (int k0 = 0; k0 < K; k0 += 32) {
#pragma unroll
        for (int p = 0; p < 2; ++p) {
            int c = w + p * 4;  // chunk: 16 rows x 32 cols = 1024 B
            gload_lds16(&A[(size_t)(m0 + c * 16 + srow) * K + k0 + scol],
                        &As[c * 512]);
            gload_lds16(&Bt[(size_t)(n0 + c * 16 + srow) * K + k0 + scol],
                        &Bs[c * 512]);
        }
        __syncthreads();

        bf16x8 af[4], bfr[4];
#pragma unroll
        for (int mt = 0; mt < 4; ++mt)
            af[mt] = *(const bf16x8*)&As[(wr * 64 + mt * 16 + l16) * 32 + q4 * 8];
#pragma unroll
        for (int nt = 0; nt < 4; ++nt)
            bfr[nt] = *(const bf16x8*)&Bs[(wc * 64 + nt * 16 + l16) * 32 + q4 * 8];
#pragma unroll
        for (int mt = 0; mt < 4; ++mt)
#pragma unroll
            for (int nt = 0; nt < 4; ++nt)
                acc[mt][nt] = mfma16(af[mt], bfr[nt], acc[mt][nt]);
        __syncthreads();
    }

    // C/D layout: col=lane&15, row=(lane>>4)*4+reg
#pragma unroll
    for (int mt = 0; mt < 4; ++mt)
#pragma unroll
        for (int nt = 0; nt < 4; ++nt) {
            int col = n0 + wc * 64 + nt * 16 + l16;
#pragma unroll
            for (int r = 0; r < 4; ++r) {
                int row = m0 + wr * 64 + mt * 16 + q4 * 4 + r;
                if (Cf && isf32)
                    Cf[(size_t)row * N + col] = acc[mt][nt][r];
                else
                    Cb[(size_t)row * N + col] = (__bf16)acc[mt][nt][r];
            }
        }
}

// Sliding-window causal attention + ALiBi, flash-style, S^T orientation.
// grid = (S/128, H, B), block = 256. Wave w owns queries [w*32, w*32+32).
// S^T = K·Q^T : C-layout gives lane l16=query, q4*4+r=key -> softmax state is
// per-lane scalar; P packs into b64 LDS writes; V staged transposed conflict-free.
__global__ __launch_bounds__(256, 3) void attn(
        const __bf16* __restrict__ qkv, __bf16* __restrict__ o) {
    // Region A (18432 B): Ks [128][72]  (QK phase) / Ps [128][72] (PV) / Ot (epilogue)
    // Region B (17408 B): Vts [64][136]
    __shared__ __align__(16) char smem[18432 + 17408];
    __bf16* Ks  = (__bf16*)smem;
    __bf16* Ps  = (__bf16*)smem;
    __bf16* Ot  = (__bf16*)smem;
    __bf16* Vts = (__bf16*)(smem + 18432);

    const int qt = blockIdx.x, h = blockIdx.y, b = blockIdx.z;
    const int t = threadIdx.x;
    const int lane = t & 63, w = t >> 6;
    const int q4 = lane >> 4, l16 = lane & 15;
    const int q0 = qt * 128;
    const int qw0 = q0 + w * 32;

    const float L2E = 1.4426950408889634f;
    const float slope = exp2f(-(float)(h + 1) * 0.5f);  // exp2(-(h+1)*8/H)
    const float scale2 = L2E * 0.125f;
    const float slope2 = slope * L2E;

    // Q as B-operand: lane l16 = query, elems = d. Straight b128 from global.
    bf16x8 qf[2][2];
    const size_t qbase = ((size_t)b * 2048 + q0) * 3072 + (size_t)h * 64;
#pragma unroll
    for (int nt = 0; nt < 2; ++nt)
#pragma unroll
        for (int kt = 0; kt < 2; ++kt)
            qf[nt][kt] = *(const bf16x8*)&qkv[qbase +
                (size_t)(w * 32 + nt * 16 + l16) * 3072 + kt * 32 + q4 * 8];

    // O^T accs: [d-tile][query-tile]; col l16=query, row q4*4+r=d
    f32x4 O[4][2] = {};
    float mrow[2] = {-1e30f, -1e30f};
    float lrow[2] = {0.0f, 0.0f};

    const int nkt = (qt < 4 ? qt : 4) + 1;
    const int ktile0 = qt - (nkt - 1);

    for (int ki = 0; ki < nkt; ++ki) {
        const int k0 = (ktile0 + ki) * 128;
        const size_t kbase = ((size_t)b * 2048 + k0) * 3072 + 1024 + (size_t)h * 64;
        const size_t vbase = ((size_t)b * 2048 + k0) * 3072 + 2048 + (size_t)h * 64;

        // per-wave valid key-16-tile range (skip fully-masked tiles)
        int mt_lo = (qw0 - 512 - k0) >> 4; if (mt_lo < 0) mt_lo = 0;
        int mt_hi = (qw0 + 31 - k0) >> 4;  if (mt_hi > 7) mt_hi = 7;

        // --- stage K natural [key][d] (b128, conflict-free) ---
#pragma unroll
        for (int it = 0; it < 2; ++it) {
            int u = it * 512 + t * 2;       // 2 chunks per thread per pass
#pragma unroll
            for (int s = 0; s < 2; ++s) {
                int uu = u + s;
                int row = uu >> 3, ch = uu & 7;
                *(uint4*)&Ks[row * 72 + ch * 8] =
                    *(const uint4*)&qkv[kbase + (size_t)row * 3072 + ch * 8];
            }
        }
        // --- stage V transposed [d][key]: lane = d, coalesced 2B loads, b128 writes ---
        {
            const unsigned short* vg = (const unsigned short*)(qkv + vbase) + lane;
#pragma unroll
            for (int i = 0; i < 4; ++i) {
                int kb = w * 4 + i;  // 8-key block
                unsigned short e[8];
#pragma unroll
                for (int j = 0; j < 8; ++j)
                    e[j] = vg[(size_t)(kb * 8 + j) * 3072];
                uint4 pk;
                pk.x = (unsigned)e[0] | ((unsigned)e[1] << 16);
                pk.y = (unsigned)e[2] | ((unsigned)e[3] << 16);
                pk.z = (unsigned)e[4] | ((unsigned)e[5] << 16);
                pk.w = (unsigned)e[6] | ((unsigned)e[7] << 16);
                *(uint4*)&Vts[lane * 136 + kb * 8] = pk;
            }
        }
        __syncthreads();  // B1: staging visible

        // --- S^T = K·Q^T : A-frag from Ks rows (lane l16 = key), B-frag = Q ---
        f32x4 sc[2][8] = {};
#pragma unroll
        for (int mt = 0; mt < 8; ++mt) {
            if (mt < mt_lo || mt > mt_hi) continue;
            bf16x8 ak0 = *(const bf16x8*)&Ks[(mt * 16 + l16) * 72 + q4 * 8];
            bf16x8 ak1 = *(const bf16x8*)&Ks[(mt * 16 + l16) * 72 + 32 + q4 * 8];
            sc[0][mt] = mfma16(ak0, qf[0][0], sc[0][mt]);
            sc[0][mt] = mfma16(ak1, qf[0][1], sc[0][mt]);
            sc[1][mt] = mfma16(ak0, qf[1][0], sc[1][mt]);
            sc[1][mt] = mfma16(ak1, qf[1][1], sc[1][mt]);
        }
        __syncthreads();  // B2: all waves done reading Ks; Ps may alias it

        // --- mask + bias + online softmax (state per lane: query = l16) ---
        float al[2];
#pragma unroll
        for (int nt = 0; nt < 2; ++nt) {
            const int qi = qw0 + nt * 16 + l16;
            const int db = qi - k0 - q4 * 4;  // delta = db - mt*16 - r
            float tmx = -1e30f;
#pragma unroll
            for (int mt = 0; mt < 8; ++mt) {
                if (mt < mt_lo || mt > mt_hi) continue;
#pragma unroll
                for (int r = 0; r < 4; ++r) {
                    int delta = db - mt * 16 - r;
                    float v = sc[nt][mt][r] * scale2 + slope2 * (float)delta;
                    v = ((unsigned)delta <= 512u) ? v : -1e30f;
                    sc[nt][mt][r] = v;
                    tmx = fmaxf(tmx, v);
                }
            }
            tmx = fmaxf(tmx, __shfl_xor(tmx, 16));
            tmx = fmaxf(tmx, __shfl_xor(tmx, 32));
            float mnew = fmaxf(mrow[nt], tmx);
            al[nt] = exp2f(mrow[nt] - mnew);
            mrow[nt] = mnew;
#pragma unroll
            for (int mtd = 0; mtd < 4; ++mtd)
#pragma unroll
                for (int r = 0; r < 4; ++r)
                    O[mtd][nt][r] *= al[nt];
        }

        // --- P write (b64, packed) + PV per 64-key half ---
        float rsum[2] = {0.0f, 0.0f};
#pragma unroll
        for (int hh = 0; hh < 2; ++hh) {
            int wlo = mt_lo > hh * 4 ? mt_lo : hh * 4;
            int whi = mt_hi < hh * 4 + 3 ? mt_hi : hh * 4 + 3;
            if (wlo > whi) continue;
            int ktl = (wlo - hh * 4) >> 1, kth = (whi - hh * 4) >> 1;

#pragma unroll
            for (int nt = 0; nt < 2; ++nt) {
                int qrow = w * 32 + nt * 16 + l16;
#pragma unroll
                for (int mt2 = 0; mt2 < 4; ++mt2) {
                    if (mt2 < ktl * 2 || mt2 > kth * 2 + 1) continue;
                    int mt = hh * 4 + mt2;
                    uint2 pkv;
                    if (mt >= mt_lo && mt <= mt_hi) {
                        float p0 = exp2f(sc[nt][mt][0] - mrow[nt]);
                        float p1 = exp2f(sc[nt][mt][1] - mrow[nt]);
                        float p2 = exp2f(sc[nt][mt][2] - mrow[nt]);
                        float p3 = exp2f(sc[nt][mt][3] - mrow[nt]);
                        rsum[nt] += (p0 + p1) + (p2 + p3);
                        pkv.x = pkbf(p0, p1);
                        pkv.y = pkbf(p2, p3);
                    } else {
                        pkv.x = 0; pkv.y = 0;
                    }
                    *(uint2*)&Ps[qrow * 72 + mt2 * 16 + q4 * 4] = pkv;
                }
            }
            // same-wave DS write->read: no barrier needed (per-wave rows)
#pragma unroll
            for (int kt = 0; kt < 2; ++kt) {
                if (kt < ktl || kt > kth) continue;
                bf16x8 bp0 = *(const bf16x8*)&Ps[(w * 32 + l16) * 72 + kt * 32 + q4 * 8];
                bf16x8 bp1 = *(const bf16x8*)&Ps[(w * 32 + 16 + l16) * 72 + kt * 32 + q4 * 8];
#pragma unroll
                for (int mtd = 0; mtd < 4; ++mtd) {
                    bf16x8 av = *(const bf16x8*)&Vts[(mtd * 16 + l16) * 136 +
                                                     hh * 64 + kt * 32 + q4 * 8];
                    O[mtd][0] = mfma16(av, bp0, O[mtd][0]);
                    O[mtd][1] = mfma16(av, bp1, O[mtd][1]);
                }
            }
        }
#pragma unroll
        for (int nt = 0; nt < 2; ++nt) {
            float rs = rsum[nt];
            rs += __shfl_xor(rs, 16);
            rs += __shfl_xor(rs, 32);
            lrow[nt] = lrow[nt] * al[nt] + rs;
        }
        __syncthreads();  // B3: PV done before next tile restages Ks/Vts
    }

    // --- epilogue: normalize, transpose O^T -> O via LDS, coalesced store ---
#pragma unroll
    for (int nt = 0; nt < 2; ++nt) {
        float inv = (lrow[nt] > 0.0f) ? 1.0f / lrow[nt] : 0.0f;
        int qrow = w * 32 + nt * 16 + l16;
#pragma unroll
        for (int mtd = 0; mtd < 4; ++mtd) {
            uint2 pkv;
            pkv.x = pkbf(O[mtd][nt][0] * inv, O[mtd][nt][1] * inv);
            pkv.y = pkbf(O[mtd][nt][2] * inv, O[mtd][nt][3] * inv);
            *(uint2*)&Ot[qrow * 72 + mtd * 16 + q4 * 4] = pkv;
        }
    }
    const size_t obase = ((size_t)b * 2048 + q0) * 1024 + (size_t)h * 64;
#pragma unroll
    for (int i = 0; i < 4; ++i) {
        int u = i * 64 + lane;
        int row = u >> 3, ch = u & 7;
        *(uint4*)&o[obase + (size_t)(w * 32 + row) * 1024 + ch * 8] =
            *(const uint4*)&Ot[(w * 32 + row) * 72 + ch * 8];
    }
}

extern "C" void kernel_launch(void* const* d_in, const int* in_sizes, int n_in,
                              void* d_out, int out_size, void* d_ws, size_t ws_size,
                              hipStream_t stream) {
    char* ws = (char*)d_ws;
    int* flag = (int*)ws;
    size_t off = 256;
    __bf16* xb  = (__bf16*)(ws + off); off += (size_t)8192 * 1024 * 2;
    __bf16* wib = (__bf16*)(ws + off); off += (size_t)3072 * 1024 * 2;
    __bf16* wob = (__bf16*)(ws + off); off += (size_t)1024 * 1024 * 2;
    __bf16* qkv = (__bf16*)(ws + off); off += (size_t)8192 * 3072 * 2;
    __bf16* o   = (__bf16*)(ws + off);

    init_flag<<<1, 1, 0, stream>>>(flag);
    int nscan = in_sizes[2] < 65536 ? in_sizes[2] : 65536;
    detect_f32<<<64, 256, 0, stream>>>((const unsigned short*)d_in[2], nscan, flag);

    cvt_bf16<<<1024, 256, 0, stream>>>(d_in[0], xb, 8192 * 1024, flag);
    cvt_bf16<<<512, 256, 0, stream>>>(d_in[1], wib, 3072 * 1024, flag);
    cvt_bf16<<<256, 256, 0, stream>>>(d_in[2], wob, 1024 * 1024, flag);

    // qkv = x @ w_in^T
    gemm_bt<<<dim3(24, 64), 256, 0, stream>>>(d_in[0], xb, d_in[1], wib,
                                              qkv, nullptr, flag, 8192, 3072, 1024);
    // attention
    attn<<<dim3(16, 16, 4), 256, 0, stream>>>(qkv, o);
    // out = o @ w_out^T (output dtype per flag)
    gemm_bt<<<dim3(8, 64), 256, 0, stream>>>(o, o, d_in[2], wob,
                                             (__bf16*)d_out, (float*)d_out, flag,
                                             8192, 1024, 1024);
}

// Round 5
// 341.896 us; speedup vs baseline: 1.0972x; 1.0972x over previous
//
#include <hip/hip_runtime.h>
#include <hip/hip_bf16.h>

// B=4, S=2048, E=1024, H=16, D=64, WIN=512.
// out = ( swa_alibi( split_heads(x @ w_in^T) ) merged ) @ w_out^T

typedef __bf16 bf16x8 __attribute__((ext_vector_type(8)));
typedef float f32x4 __attribute__((ext_vector_type(4)));

__device__ __forceinline__ f32x4 mfma16(bf16x8 a, bf16x8 b, f32x4 c) {
    return __builtin_amdgcn_mfma_f32_16x16x32_bf16(a, b, c, 0, 0, 0);
}

__device__ __forceinline__ void gload_lds16(const void* g, void* l) {
    __builtin_amdgcn_global_load_lds(
        (const __attribute__((address_space(1))) unsigned int*)(unsigned long long)g,
        (__attribute__((address_space(3))) unsigned int*)(unsigned int)(unsigned long long)l,
        16, 0, 0);
}

__device__ __forceinline__ unsigned pkbf(float a, float b) {
    unsigned short ua = __builtin_bit_cast(unsigned short, (__bf16)a);
    unsigned short ub = __builtin_bit_cast(unsigned short, (__bf16)b);
    return (unsigned)ua | ((unsigned)ub << 16);
}

__global__ void init_flag(int* flag) { *flag = 0; }

// f32 data read as bf16 halfwords shows huge exponents (p~0.45 per halfword).
__global__ void detect_f32(const unsigned short* __restrict__ w, int n, int* flag) {
    int i = blockIdx.x * blockDim.x + threadIdx.x;
    int hit = 0;
    for (; i < n; i += gridDim.x * blockDim.x) {
        int e = (w[i] >> 7) & 0xFF;
        if (e >= 0x8D) hit = 1;
    }
    unsigned long long m = __ballot(hit);
    if (m != 0 && (threadIdx.x & 63) == 0) atomicOr(flag, 1);
}

// Single launch: converts all three inputs f32->bf16 iff flag set; else no-op.
__global__ void cvt_all(const void* __restrict__ x, const void* __restrict__ wi,
                        const void* __restrict__ wo, __bf16* __restrict__ xb,
                        __bf16* __restrict__ wib, __bf16* __restrict__ wob,
                        const int* __restrict__ flag) {
    if (*flag == 0) return;
    const int XN = 8192 * 1024, WI = 3072 * 1024, WO = 1024 * 1024;
    const int stride = gridDim.x * blockDim.x;
    int i0 = blockIdx.x * blockDim.x + threadIdx.x;
    for (int j = i0; j < XN; j += stride) xb[j] = (__bf16)((const float*)x)[j];
    for (int j = i0; j < WI; j += stride) wib[j] = (__bf16)((const float*)wi)[j];
    for (int j = i0; j < WO; j += stride) wob[j] = (__bf16)((const float*)wo)[j];
}

// C[M,N] = A[M,K] @ Bt[N,K]^T. m97 pattern: 128x128 tile, BK=32, unpadded LDS,
// global_load_lds width-16 staging.
__global__ __launch_bounds__(256, 3) void gemm_bt(
        const void* __restrict__ Araw, const __bf16* __restrict__ Acvt,
        const void* __restrict__ Braw, const __bf16* __restrict__ Bcvt,
        __bf16* __restrict__ Cb, float* __restrict__ Cf,
        const int* __restrict__ flagp, int M, int N, int K) {
    __shared__ __align__(16) __bf16 As[128 * 32];
    __shared__ __align__(16) __bf16 Bs[128 * 32];

    const int t = threadIdx.x;
    const int lane = t & 63;
    const int w = t >> 6;
    const int wr = w >> 1, wc = w & 1;
    const int q4 = lane >> 4, l16 = lane & 15;
    const int m0 = blockIdx.y * 128, n0 = blockIdx.x * 128;
    const bool isf32 = (*flagp != 0);
    const __bf16* A = isf32 ? Acvt : (const __bf16*)Araw;
    const __bf16* Bt = isf32 ? Bcvt : (const __bf16*)Braw;

    f32x4 acc[4][4] = {};
    const int srow = lane >> 2, scol = (lane & 3) * 8;

    for (int k0 = 0; k0 < K; k0 += 32) {
#pragma unroll
        for (int p = 0; p < 2; ++p) {
            int c = w + p * 4;  // 16 rows x 32 cols = 1024 B chunk
            gload_lds16(&A[(size_t)(m0 + c * 16 + srow) * K + k0 + scol], &As[c * 512]);
            gload_lds16(&Bt[(size_t)(n0 + c * 16 + srow) * K + k0 + scol], &Bs[c * 512]);
        }
        __syncthreads();

        bf16x8 af[4], bfr[4];
#pragma unroll
        for (int mt = 0; mt < 4; ++mt)
            af[mt] = *(const bf16x8*)&As[(wr * 64 + mt * 16 + l16) * 32 + q4 * 8];
#pragma unroll
        for (int nt = 0; nt < 4; ++nt)
            bfr[nt] = *(const bf16x8*)&Bs[(wc * 64 + nt * 16 + l16) * 32 + q4 * 8];
#pragma unroll
        for (int mt = 0; mt < 4; ++mt)
#pragma unroll
            for (int nt = 0; nt < 4; ++nt)
                acc[mt][nt] = mfma16(af[mt], bfr[nt], acc[mt][nt]);
        __syncthreads();
    }

#pragma unroll
    for (int mt = 0; mt < 4; ++mt)
#pragma unroll
        for (int nt = 0; nt < 4; ++nt) {
            int col = n0 + wc * 64 + nt * 16 + l16;
#pragma unroll
            for (int r = 0; r < 4; ++r) {
                int row = m0 + wr * 64 + mt * 16 + q4 * 4 + r;
                if (Cf && isf32)
                    Cf[(size_t)row * N + col] = acc[mt][nt][r];
                else
                    Cb[(size_t)row * N + col] = (__bf16)acc[mt][nt][r];
            }
        }
}

// Sliding-window causal attention + ALiBi, flash-style, S^T orientation,
// 64-key sub-iterations, register-prefetched K/V staging, swizzled LDS.
// grid = (S/128, H, B), block = 256 (wave w owns queries [w*32, w*32+32)).
__global__ __launch_bounds__(256, 3) void attn(
        const __bf16* __restrict__ qkv, __bf16* __restrict__ o) {
    // Ks : 128 keys x 64 d, pitch 64, chunk-swizzled   [0, 16384)
    // Vts: 64 d x 128 keys, pitch 136, chunk-swizzled  [16384, 33792)
    // Ps : 128 q x 64 keys, pitch 72                   [33792, 52224)
    // Ot : epilogue transpose buffer, aliases Ks
    __shared__ __align__(16) char smem[52224];
    __bf16* Ks  = (__bf16*)smem;
    __bf16* Vts = (__bf16*)(smem + 16384);
    __bf16* Ps  = (__bf16*)(smem + 33792);
    __bf16* Ot  = (__bf16*)smem;

    const int qt = blockIdx.x, h = blockIdx.y, b = blockIdx.z;
    const int t = threadIdx.x;
    const int lane = t & 63, w = t >> 6;
    const int q4 = lane >> 4, l16 = lane & 15;
    const int q0 = qt * 128, qw0 = q0 + w * 32;

    const float L2E = 1.4426950408889634f;
    const float slope2 = exp2f(-(float)(h + 1) * 0.5f) * L2E;  // alibi slope * log2e
    const float scale2 = L2E * 0.125f;                         // log2e / sqrt(64)

    // staging coords: thread handles chunk (row = p*32+srow, d-block scb)
    const int srow = t >> 3, scb = t & 7;
    const int ksoff = (scb ^ (srow & 7)) << 3;  // K swizzle (row&7 == srow&7 for all p)

    // Q as B-operand (lane l16 = query, k = d), straight b128 from global
    bf16x8 qf[2][2];
    const size_t qbase = ((size_t)b * 2048 + q0) * 3072 + (size_t)h * 64;
#pragma unroll
    for (int nt = 0; nt < 2; ++nt)
#pragma unroll
        for (int kt = 0; kt < 2; ++kt)
            qf[nt][kt] = *(const bf16x8*)&qkv[qbase +
                (size_t)(w * 32 + nt * 16 + l16) * 3072 + kt * 32 + q4 * 8];

    f32x4 O[4][2] = {};  // O^T: [d-tile][q-tile], col l16=q, row q4*4+r=d
    float mrow[2] = {-1e30f, -1e30f}, lrow[2] = {0.0f, 0.0f};

    const int nkt = (qt < 4 ? qt : 4) + 1;
    const int ktile0 = qt - (nkt - 1);
    const size_t bh = (size_t)b * 2048 * 3072 + (size_t)h * 64;

    uint4 kpre[4], vpre[4];

    // prologue: load + commit tile 0
    {
        const size_t kb = bh + (size_t)(ktile0 * 128) * 3072 + 1024;
#pragma unroll
        for (int p = 0; p < 4; ++p)
            kpre[p] = *(const uint4*)&qkv[kb + (size_t)(p * 32 + srow) * 3072 + scb * 8];
#pragma unroll
        for (int p = 0; p < 4; ++p)
            vpre[p] = *(const uint4*)&qkv[kb + 1024 + (size_t)(p * 32 + srow) * 3072 + scb * 8];
#pragma unroll
        for (int p = 0; p < 4; ++p) {
            *(uint4*)&Ks[(p * 32 + srow) * 64 + ksoff] = kpre[p];
            const __bf16* ve = (const __bf16*)&vpre[p];
            int R = p * 4 + (srow >> 3);
#pragma unroll
            for (int j = 0; j < 8; ++j)
                Vts[(scb * 8 + j) * 136 + ((R ^ scb) << 3) + (srow & 7)] = ve[j];
        }
    }
    __syncthreads();

    for (int ki = 0; ki < nkt; ++ki) {
        const int k0 = (ktile0 + ki) * 128;
        if (ki + 1 < nkt) {  // issue next tile's loads (no wait)
            const size_t kb = bh + (size_t)(k0 + 128) * 3072 + 1024;
#pragma unroll
            for (int p = 0; p < 4; ++p)
                kpre[p] = *(const uint4*)&qkv[kb + (size_t)(p * 32 + srow) * 3072 + scb * 8];
#pragma unroll
            for (int p = 0; p < 4; ++p)
                vpre[p] = *(const uint4*)&qkv[kb + 1024 + (size_t)(p * 32 + srow) * 3072 + scb * 8];
        }

#pragma unroll
        for (int hh = 0; hh < 2; ++hh) {
            const int ks0 = k0 + hh * 64;
            if (qw0 + 31 < ks0 || qw0 - 512 > ks0 + 63) continue;  // wave-uniform skip

            // S^T = K·Q^T over this 64-key subtile
            f32x4 sc[2][4] = {};
#pragma unroll
            for (int mt = 0; mt < 4; ++mt) {
                int krow = hh * 64 + mt * 16 + l16;
                bf16x8 ak0 = *(const bf16x8*)&Ks[krow * 64 + ((q4 ^ (l16 & 7)) << 3)];
                bf16x8 ak1 = *(const bf16x8*)&Ks[krow * 64 + (((4 + q4) ^ (l16 & 7)) << 3)];
                sc[0][mt] = mfma16(ak0, qf[0][0], sc[0][mt]);
                sc[0][mt] = mfma16(ak1, qf[0][1], sc[0][mt]);
                sc[1][mt] = mfma16(ak0, qf[1][0], sc[1][mt]);
                sc[1][mt] = mfma16(ak1, qf[1][1], sc[1][mt]);
            }

            // mask + bias + online-softmax update (per-lane state, query = l16)
            float al[2];
#pragma unroll
            for (int nt = 0; nt < 2; ++nt) {
                const int qi = qw0 + nt * 16 + l16;
                const int db = qi - ks0 - q4 * 4;  // delta = db - mt*16 - r
                float tmx = -1e30f;
#pragma unroll
                for (int mt = 0; mt < 4; ++mt)
#pragma unroll
                    for (int r = 0; r < 4; ++r) {
                        int delta = db - mt * 16 - r;
                        float v = sc[nt][mt][r] * scale2 + slope2 * (float)delta;
                        v = ((unsigned)delta <= 512u) ? v : -1e30f;
                        sc[nt][mt][r] = v;
                        tmx = fmaxf(tmx, v);
                    }
                tmx = fmaxf(tmx, __shfl_xor(tmx, 16));
                tmx = fmaxf(tmx, __shfl_xor(tmx, 32));
                float mnew = fmaxf(mrow[nt], tmx);
                al[nt] = exp2f(mrow[nt] - mnew);
                mrow[nt] = mnew;
#pragma unroll
                for (int mtd = 0; mtd < 4; ++mtd)
                    O[mtd][nt] *= al[nt];
            }

            // P (packed b64 writes into own 32-row strip) + row-sum
            float rsum[2] = {0.0f, 0.0f};
#pragma unroll
            for (int nt = 0; nt < 2; ++nt) {
                int qrow = w * 32 + nt * 16 + l16;
#pragma unroll
                for (int mt = 0; mt < 4; ++mt) {
                    float p0 = exp2f(sc[nt][mt][0] - mrow[nt]);
                    float p1 = exp2f(sc[nt][mt][1] - mrow[nt]);
                    float p2 = exp2f(sc[nt][mt][2] - mrow[nt]);
                    float p3 = exp2f(sc[nt][mt][3] - mrow[nt]);
                    rsum[nt] += (p0 + p1) + (p2 + p3);
                    uint2 pk;
                    pk.x = pkbf(p0, p1);
                    pk.y = pkbf(p2, p3);
                    *(uint2*)&Ps[qrow * 72 + mt * 16 + q4 * 4] = pk;
                }
            }

            // PV: A = V^T (swizzled Vts), B = P^T (same-wave Ps strip; in-order DS)
#pragma unroll
            for (int kt = 0; kt < 2; ++kt) {
                bf16x8 bp0 = *(const bf16x8*)&Ps[(w * 32 + l16) * 72 + kt * 32 + q4 * 8];
                bf16x8 bp1 = *(const bf16x8*)&Ps[(w * 32 + 16 + l16) * 72 + kt * 32 + q4 * 8];
#pragma unroll
                for (int mtd = 0; mtd < 4; ++mtd) {
                    int d = mtd * 16 + l16;
                    int kb2 = (hh * 8 + kt * 4 + q4) ^ ((mtd * 2 + (l16 >> 3)) & 7);
                    bf16x8 av = *(const bf16x8*)&Vts[d * 136 + (kb2 << 3)];
                    O[mtd][0] = mfma16(av, bp0, O[mtd][0]);
                    O[mtd][1] = mfma16(av, bp1, O[mtd][1]);
                }
            }
#pragma unroll
            for (int nt = 0; nt < 2; ++nt) {
                float rs = rsum[nt];
                rs += __shfl_xor(rs, 16);
                rs += __shfl_xor(rs, 32);
                lrow[nt] = lrow[nt] * al[nt] + rs;
            }
        }

        __syncthreads();  // all waves done reading Ks/Vts
        if (ki + 1 < nkt) {
#pragma unroll
            for (int p = 0; p < 4; ++p) {
                *(uint4*)&Ks[(p * 32 + srow) * 64 + ksoff] = kpre[p];
                const __bf16* ve = (const __bf16*)&vpre[p];
                int R = p * 4 + (srow >> 3);
#pragma unroll
                for (int j = 0; j < 8; ++j)
                    Vts[(scb * 8 + j) * 136 + ((R ^ scb) << 3) + (srow & 7)] = ve[j];
            }
        }
        __syncthreads();  // commits visible
    }

    // epilogue: normalize, transpose O^T -> O via swizzled Ot (aliases Ks; all
    // accesses stay within this wave's 32-query strip -> no barrier needed)
#pragma unroll
    for (int nt = 0; nt < 2; ++nt) {
        float inv = (lrow[nt] > 0.0f) ? 1.0f / lrow[nt] : 0.0f;
        int qrow = w * 32 + nt * 16 + l16;
#pragma unroll
        for (int mtd = 0; mtd < 4; ++mtd) {
            int chunk = (mtd * 2 + (q4 >> 1)) ^ (l16 & 7);
            uint2 pk;
            pk.x = pkbf(O[mtd][nt][0] * inv, O[mtd][nt][1] * inv);
            pk.y = pkbf(O[mtd][nt][2] * inv, O[mtd][nt][3] * inv);
            *(uint2*)&Ot[qrow * 64 + (chunk << 3) + (q4 & 1) * 4] = pk;
        }
    }
    const size_t obase = ((size_t)b * 2048 + q0) * 1024 + (size_t)h * 64;
#pragma unroll
    for (int i = 0; i < 4; ++i) {
        int u = i * 64 + lane;
        int row = u >> 3, ch = u & 7;
        int q = w * 32 + row;
        *(uint4*)&o[obase + (size_t)q * 1024 + ch * 8] =
            *(const uint4*)&Ot[q * 64 + ((ch ^ (row & 7)) << 3)];
    }
}

extern "C" void kernel_launch(void* const* d_in, const int* in_sizes, int n_in,
                              void* d_out, int out_size, void* d_ws, size_t ws_size,
                              hipStream_t stream) {
    char* ws = (char*)d_ws;
    int* flag = (int*)ws;
    size_t off = 256;
    __bf16* xb  = (__bf16*)(ws + off); off += (size_t)8192 * 1024 * 2;
    __bf16* wib = (__bf16*)(ws + off); off += (size_t)3072 * 1024 * 2;
    __bf16* wob = (__bf16*)(ws + off); off += (size_t)1024 * 1024 * 2;
    __bf16* qkv = (__bf16*)(ws + off); off += (size_t)8192 * 3072 * 2;
    __bf16* o   = (__bf16*)(ws + off);

    init_flag<<<1, 1, 0, stream>>>(flag);
    int nscan = in_sizes[2] < 65536 ? in_sizes[2] : 65536;
    detect_f32<<<16, 256, 0, stream>>>((const unsigned short*)d_in[2], nscan, flag);
    cvt_all<<<1024, 256, 0, stream>>>(d_in[0], d_in[1], d_in[2], xb, wib, wob, flag);

    // qkv = x @ w_in^T
    gemm_bt<<<dim3(24, 64), 256, 0, stream>>>(d_in[0], xb, d_in[1], wib,
                                              qkv, nullptr, flag, 8192, 3072, 1024);
    // attention
    attn<<<dim3(16, 16, 4), 256, 0, stream>>>(qkv, o);
    // out = o @ w_out^T (output dtype per flag)
    gemm_bt<<<dim3(8, 64), 256, 0, stream>>>(o, o, d_in[2], wob,
                                             (__bf16*)d_out, (float*)d_out, flag,
                                             8192, 1024, 1024);
}

// Round 6
// 279.517 us; speedup vs baseline: 1.3420x; 1.2232x over previous
//
#include <hip/hip_runtime.h>
#include <hip/hip_bf16.h>

// B=4, S=2048, E=1024, H=16, D=64, WIN=512.
// out = ( swa_alibi( split_heads(x @ w_in^T) ) merged ) @ w_out^T

typedef __bf16 bf16x8 __attribute__((ext_vector_type(8)));
typedef float f32x4 __attribute__((ext_vector_type(4)));

__device__ __forceinline__ f32x4 mfma16(bf16x8 a, bf16x8 b, f32x4 c) {
    return __builtin_amdgcn_mfma_f32_16x16x32_bf16(a, b, c, 0, 0, 0);
}

__device__ __forceinline__ void gload_lds16(const void* g, void* l) {
    __builtin_amdgcn_global_load_lds(
        (const __attribute__((address_space(1))) unsigned int*)(unsigned long long)g,
        (__attribute__((address_space(3))) unsigned int*)(unsigned int)(unsigned long long)l,
        16, 0, 0);
}

__device__ __forceinline__ unsigned pkbf(float a, float b) {
    unsigned short ua = __builtin_bit_cast(unsigned short, (__bf16)a);
    unsigned short ub = __builtin_bit_cast(unsigned short, (__bf16)b);
    return (unsigned)ua | ((unsigned)ub << 16);
}

__global__ void init_flag(int* flag) { *flag = 0; }

// f32 data read as bf16 halfwords shows huge exponents (p~0.45 per halfword).
__global__ void detect_f32(const unsigned short* __restrict__ w, int n, int* flag) {
    int i = blockIdx.x * blockDim.x + threadIdx.x;
    int hit = 0;
    for (; i < n; i += gridDim.x * blockDim.x) {
        int e = (w[i] >> 7) & 0xFF;
        if (e >= 0x8D) hit = 1;
    }
    unsigned long long m = __ballot(hit);
    if (m != 0 && (threadIdx.x & 63) == 0) atomicOr(flag, 1);
}

// Single launch: converts all three inputs f32->bf16 iff flag set; else no-op.
__global__ void cvt_all(const void* __restrict__ x, const void* __restrict__ wi,
                        const void* __restrict__ wo, __bf16* __restrict__ xb,
                        __bf16* __restrict__ wib, __bf16* __restrict__ wob,
                        const int* __restrict__ flag) {
    if (*flag == 0) return;
    const int XN = 8192 * 1024, WI = 3072 * 1024, WO = 1024 * 1024;
    const int stride = gridDim.x * blockDim.x;
    int i0 = blockIdx.x * blockDim.x + threadIdx.x;
    for (int j = i0; j < XN; j += stride) xb[j] = (__bf16)((const float*)x)[j];
    for (int j = i0; j < WI; j += stride) wib[j] = (__bf16)((const float*)wi)[j];
    for (int j = i0; j < WO; j += stride) wob[j] = (__bf16)((const float*)wo)[j];
}

// C[M,N] = A[M,K] @ Bt[N,K]^T. m97 pattern: 128x128 tile, BK=32, unpadded LDS,
// global_load_lds width-16 staging.
__global__ __launch_bounds__(256, 3) void gemm_bt(
        const void* __restrict__ Araw, const __bf16* __restrict__ Acvt,
        const void* __restrict__ Braw, const __bf16* __restrict__ Bcvt,
        __bf16* __restrict__ Cb, float* __restrict__ Cf,
        const int* __restrict__ flagp, int M, int N, int K) {
    __shared__ __align__(16) __bf16 As[128 * 32];
    __shared__ __align__(16) __bf16 Bs[128 * 32];

    const int t = threadIdx.x;
    const int lane = t & 63;
    const int w = t >> 6;
    const int wr = w >> 1, wc = w & 1;
    const int q4 = lane >> 4, l16 = lane & 15;
    const int m0 = blockIdx.y * 128, n0 = blockIdx.x * 128;
    const bool isf32 = (*flagp != 0);
    const __bf16* A = isf32 ? Acvt : (const __bf16*)Araw;
    const __bf16* Bt = isf32 ? Bcvt : (const __bf16*)Braw;

    f32x4 acc[4][4] = {};
    const int srow = lane >> 2, scol = (lane & 3) * 8;

    for (int k0 = 0; k0 < K; k0 += 32) {
#pragma unroll
        for (int p = 0; p < 2; ++p) {
            int c = w + p * 4;  // 16 rows x 32 cols = 1024 B chunk
            gload_lds16(&A[(size_t)(m0 + c * 16 + srow) * K + k0 + scol], &As[c * 512]);
            gload_lds16(&Bt[(size_t)(n0 + c * 16 + srow) * K + k0 + scol], &Bs[c * 512]);
        }
        __syncthreads();

        bf16x8 af[4], bfr[4];
#pragma unroll
        for (int mt = 0; mt < 4; ++mt)
            af[mt] = *(const bf16x8*)&As[(wr * 64 + mt * 16 + l16) * 32 + q4 * 8];
#pragma unroll
        for (int nt = 0; nt < 4; ++nt)
            bfr[nt] = *(const bf16x8*)&Bs[(wc * 64 + nt * 16 + l16) * 32 + q4 * 8];
#pragma unroll
        for (int mt = 0; mt < 4; ++mt)
#pragma unroll
            for (int nt = 0; nt < 4; ++nt)
                acc[mt][nt] = mfma16(af[mt], bfr[nt], acc[mt][nt]);
        __syncthreads();
    }

#pragma unroll
    for (int mt = 0; mt < 4; ++mt)
#pragma unroll
        for (int nt = 0; nt < 4; ++nt) {
            int col = n0 + wc * 64 + nt * 16 + l16;
#pragma unroll
            for (int r = 0; r < 4; ++r) {
                int row = m0 + wr * 64 + mt * 16 + q4 * 4 + r;
                if (Cf && isf32)
                    Cf[(size_t)row * N + col] = acc[mt][nt][r];
                else
                    Cb[(size_t)row * N + col] = (__bf16)acc[mt][nt][r];
            }
        }
}

// Sliding-window causal attention + ALiBi, flash-style, S^T orientation,
// 64-key sub-iterations, register-prefetched K/V staging, swizzled LDS.
// grid = (S/128, H, B), block = 256 (wave w owns queries [w*32, w*32+32)).
// launch_bounds (256,2): prefetch regs (kpre/vpre, 32 VGPRs) live across the
// compute phase — (256,3)'s ~170-reg cap spilled them every tile (150 MB/launch
// scratch traffic, R5 counters). 256-reg budget fits all live state.
__global__ __launch_bounds__(256, 2) void attn(
        const __bf16* __restrict__ qkv, __bf16* __restrict__ o) {
    // Ks : 128 keys x 64 d, pitch 64, chunk-swizzled   [0, 16384)
    // Vts: 64 d x 128 keys, pitch 136, chunk-swizzled  [16384, 33792)
    // Ps : 128 q x 64 keys, pitch 72                   [33792, 52224)
    // Ot : epilogue transpose buffer, aliases Ks
    __shared__ __align__(16) char smem[52224];
    __bf16* Ks  = (__bf16*)smem;
    __bf16* Vts = (__bf16*)(smem + 16384);
    __bf16* Ps  = (__bf16*)(smem + 33792);
    __bf16* Ot  = (__bf16*)smem;

    const int qt = blockIdx.x, h = blockIdx.y, b = blockIdx.z;
    const int t = threadIdx.x;
    const int lane = t & 63, w = t >> 6;
    const int q4 = lane >> 4, l16 = lane & 15;
    const int q0 = qt * 128, qw0 = q0 + w * 32;

    const float L2E = 1.4426950408889634f;
    const float slope2 = exp2f(-(float)(h + 1) * 0.5f) * L2E;  // alibi slope * log2e
    const float scale2 = L2E * 0.125f;                         // log2e / sqrt(64)

    // staging coords: thread handles chunk (row = p*32+srow, d-block scb)
    const int srow = t >> 3, scb = t & 7;
    const int ksoff = (scb ^ (srow & 7)) << 3;  // K swizzle (row&7 == srow&7 for all p)

    // Q as B-operand (lane l16 = query, k = d), straight b128 from global
    bf16x8 qf[2][2];
    const size_t qbase = ((size_t)b * 2048 + q0) * 3072 + (size_t)h * 64;
#pragma unroll
    for (int nt = 0; nt < 2; ++nt)
#pragma unroll
        for (int kt = 0; kt < 2; ++kt)
            qf[nt][kt] = *(const bf16x8*)&qkv[qbase +
                (size_t)(w * 32 + nt * 16 + l16) * 3072 + kt * 32 + q4 * 8];

    f32x4 O[4][2] = {};  // O^T: [d-tile][q-tile], col l16=q, row q4*4+r=d
    float mrow[2] = {-1e30f, -1e30f}, lrow[2] = {0.0f, 0.0f};

    const int nkt = (qt < 4 ? qt : 4) + 1;
    const int ktile0 = qt - (nkt - 1);
    const size_t bh = (size_t)b * 2048 * 3072 + (size_t)h * 64;

    uint4 kpre[4], vpre[4];

    // prologue: load + commit tile 0
    {
        const size_t kb = bh + (size_t)(ktile0 * 128) * 3072 + 1024;
#pragma unroll
        for (int p = 0; p < 4; ++p)
            kpre[p] = *(const uint4*)&qkv[kb + (size_t)(p * 32 + srow) * 3072 + scb * 8];
#pragma unroll
        for (int p = 0; p < 4; ++p)
            vpre[p] = *(const uint4*)&qkv[kb + 1024 + (size_t)(p * 32 + srow) * 3072 + scb * 8];
#pragma unroll
        for (int p = 0; p < 4; ++p) {
            *(uint4*)&Ks[(p * 32 + srow) * 64 + ksoff] = kpre[p];
            const __bf16* ve = (const __bf16*)&vpre[p];
            int R = p * 4 + (srow >> 3);
#pragma unroll
            for (int j = 0; j < 8; ++j)
                Vts[(scb * 8 + j) * 136 + ((R ^ scb) << 3) + (srow & 7)] = ve[j];
        }
    }
    __syncthreads();

    for (int ki = 0; ki < nkt; ++ki) {
        const int k0 = (ktile0 + ki) * 128;
        if (ki + 1 < nkt) {  // issue next tile's loads (no wait)
            const size_t kb = bh + (size_t)(k0 + 128) * 3072 + 1024;
#pragma unroll
            for (int p = 0; p < 4; ++p)
                kpre[p] = *(const uint4*)&qkv[kb + (size_t)(p * 32 + srow) * 3072 + scb * 8];
#pragma unroll
            for (int p = 0; p < 4; ++p)
                vpre[p] = *(const uint4*)&qkv[kb + 1024 + (size_t)(p * 32 + srow) * 3072 + scb * 8];
        }

#pragma unroll
        for (int hh = 0; hh < 2; ++hh) {
            const int ks0 = k0 + hh * 64;
            if (qw0 + 31 < ks0 || qw0 - 512 > ks0 + 63) continue;  // wave-uniform skip

            // S^T = K·Q^T over this 64-key subtile
            f32x4 sc[2][4] = {};
#pragma unroll
            for (int mt = 0; mt < 4; ++mt) {
                int krow = hh * 64 + mt * 16 + l16;
                bf16x8 ak0 = *(const bf16x8*)&Ks[krow * 64 + ((q4 ^ (l16 & 7)) << 3)];
                bf16x8 ak1 = *(const bf16x8*)&Ks[krow * 64 + (((4 + q4) ^ (l16 & 7)) << 3)];
                sc[0][mt] = mfma16(ak0, qf[0][0], sc[0][mt]);
                sc[0][mt] = mfma16(ak1, qf[0][1], sc[0][mt]);
                sc[1][mt] = mfma16(ak0, qf[1][0], sc[1][mt]);
                sc[1][mt] = mfma16(ak1, qf[1][1], sc[1][mt]);
            }

            // mask + bias + online-softmax update (per-lane state, query = l16)
            float al[2];
#pragma unroll
            for (int nt = 0; nt < 2; ++nt) {
                const int qi = qw0 + nt * 16 + l16;
                const int db = qi - ks0 - q4 * 4;  // delta = db - mt*16 - r
                float tmx = -1e30f;
#pragma unroll
                for (int mt = 0; mt < 4; ++mt)
#pragma unroll
                    for (int r = 0; r < 4; ++r) {
                        int delta = db - mt * 16 - r;
                        float v = sc[nt][mt][r] * scale2 + slope2 * (float)delta;
                        v = ((unsigned)delta <= 512u) ? v : -1e30f;
                        sc[nt][mt][r] = v;
                        tmx = fmaxf(tmx, v);
                    }
                tmx = fmaxf(tmx, __shfl_xor(tmx, 16));
                tmx = fmaxf(tmx, __shfl_xor(tmx, 32));
                float mnew = fmaxf(mrow[nt], tmx);
                al[nt] = exp2f(mrow[nt] - mnew);
                mrow[nt] = mnew;
#pragma unroll
                for (int mtd = 0; mtd < 4; ++mtd)
                    O[mtd][nt] *= al[nt];
            }

            // P (packed b64 writes into own 32-row strip) + row-sum
            float rsum[2] = {0.0f, 0.0f};
#pragma unroll
            for (int nt = 0; nt < 2; ++nt) {
                int qrow = w * 32 + nt * 16 + l16;
#pragma unroll
                for (int mt = 0; mt < 4; ++mt) {
                    float p0 = exp2f(sc[nt][mt][0] - mrow[nt]);
                    float p1 = exp2f(sc[nt][mt][1] - mrow[nt]);
                    float p2 = exp2f(sc[nt][mt][2] - mrow[nt]);
                    float p3 = exp2f(sc[nt][mt][3] - mrow[nt]);
                    rsum[nt] += (p0 + p1) + (p2 + p3);
                    uint2 pk;
                    pk.x = pkbf(p0, p1);
                    pk.y = pkbf(p2, p3);
                    *(uint2*)&Ps[qrow * 72 + mt * 16 + q4 * 4] = pk;
                }
            }

            // PV: A = V^T (swizzled Vts), B = P^T (same-wave Ps strip; in-order DS)
#pragma unroll
            for (int kt = 0; kt < 2; ++kt) {
                bf16x8 bp0 = *(const bf16x8*)&Ps[(w * 32 + l16) * 72 + kt * 32 + q4 * 8];
                bf16x8 bp1 = *(const bf16x8*)&Ps[(w * 32 + 16 + l16) * 72 + kt * 32 + q4 * 8];
#pragma unroll
                for (int mtd = 0; mtd < 4; ++mtd) {
                    int d = mtd * 16 + l16;
                    int kb2 = (hh * 8 + kt * 4 + q4) ^ ((mtd * 2 + (l16 >> 3)) & 7);
                    bf16x8 av = *(const bf16x8*)&Vts[d * 136 + (kb2 << 3)];
                    O[mtd][0] = mfma16(av, bp0, O[mtd][0]);
                    O[mtd][1] = mfma16(av, bp1, O[mtd][1]);
                }
            }
#pragma unroll
            for (int nt = 0; nt < 2; ++nt) {
                float rs = rsum[nt];
                rs += __shfl_xor(rs, 16);
                rs += __shfl_xor(rs, 32);
                lrow[nt] = lrow[nt] * al[nt] + rs;
            }
        }

        __syncthreads();  // all waves done reading Ks/Vts
        if (ki + 1 < nkt) {
#pragma unroll
            for (int p = 0; p < 4; ++p) {
                *(uint4*)&Ks[(p * 32 + srow) * 64 + ksoff] = kpre[p];
                const __bf16* ve = (const __bf16*)&vpre[p];
                int R = p * 4 + (srow >> 3);
#pragma unroll
                for (int j = 0; j < 8; ++j)
                    Vts[(scb * 8 + j) * 136 + ((R ^ scb) << 3) + (srow & 7)] = ve[j];
            }
        }
        __syncthreads();  // commits visible
    }

    // epilogue: normalize, transpose O^T -> O via swizzled Ot (aliases Ks; all
    // accesses stay within this wave's 32-query strip -> no barrier needed)
#pragma unroll
    for (int nt = 0; nt < 2; ++nt) {
        float inv = (lrow[nt] > 0.0f) ? 1.0f / lrow[nt] : 0.0f;
        int qrow = w * 32 + nt * 16 + l16;
#pragma unroll
        for (int mtd = 0; mtd < 4; ++mtd) {
            int chunk = (mtd * 2 + (q4 >> 1)) ^ (l16 & 7);
            uint2 pk;
            pk.x = pkbf(O[mtd][nt][0] * inv, O[mtd][nt][1] * inv);
            pk.y = pkbf(O[mtd][nt][2] * inv, O[mtd][nt][3] * inv);
            *(uint2*)&Ot[qrow * 64 + (chunk << 3) + (q4 & 1) * 4] = pk;
        }
    }
    const size_t obase = ((size_t)b * 2048 + q0) * 1024 + (size_t)h * 64;
#pragma unroll
    for (int i = 0; i < 4; ++i) {
        int u = i * 64 + lane;
        int row = u >> 3, ch = u & 7;
        int q = w * 32 + row;
        *(uint4*)&o[obase + (size_t)q * 1024 + ch * 8] =
            *(const uint4*)&Ot[q * 64 + ((ch ^ (row & 7)) << 3)];
    }
}

extern "C" void kernel_launch(void* const* d_in, const int* in_sizes, int n_in,
                              void* d_out, int out_size, void* d_ws, size_t ws_size,
                              hipStream_t stream) {
    char* ws = (char*)d_ws;
    int* flag = (int*)ws;
    size_t off = 256;
    __bf16* xb  = (__bf16*)(ws + off); off += (size_t)8192 * 1024 * 2;
    __bf16* wib = (__bf16*)(ws + off); off += (size_t)3072 * 1024 * 2;
    __bf16* wob = (__bf16*)(ws + off); off += (size_t)1024 * 1024 * 2;
    __bf16* qkv = (__bf16*)(ws + off); off += (size_t)8192 * 3072 * 2;
    __bf16* o   = (__bf16*)(ws + off);

    init_flag<<<1, 1, 0, stream>>>(flag);
    int nscan = in_sizes[2] < 65536 ? in_sizes[2] : 65536;
    detect_f32<<<16, 256, 0, stream>>>((const unsigned short*)d_in[2], nscan, flag);
    cvt_all<<<1024, 256, 0, stream>>>(d_in[0], d_in[1], d_in[2], xb, wib, wob, flag);

    // qkv = x @ w_in^T
    gemm_bt<<<dim3(24, 64), 256, 0, stream>>>(d_in[0], xb, d_in[1], wib,
                                              qkv, nullptr, flag, 8192, 3072, 1024);
    // attention
    attn<<<dim3(16, 16, 4), 256, 0, stream>>>(qkv, o);
    // out = o @ w_out^T (output dtype per flag)
    gemm_bt<<<dim3(8, 64), 256, 0, stream>>>(o, o, d_in[2], wob,
                                             (__bf16*)d_out, (float*)d_out, flag,
                                             8192, 1024, 1024);
}

// Round 7
// 266.675 us; speedup vs baseline: 1.4067x; 1.0482x over previous
//
#include <hip/hip_runtime.h>
#include <hip/hip_bf16.h>

// B=4, S=2048, E=1024, H=16, D=64, WIN=512.
// out = ( swa_alibi( split_heads(x @ w_in^T) ) merged ) @ w_out^T

typedef __bf16 bf16x8 __attribute__((ext_vector_type(8)));
typedef float f32x4 __attribute__((ext_vector_type(4)));

__device__ __forceinline__ f32x4 mfma16(bf16x8 a, bf16x8 b, f32x4 c) {
    return __builtin_amdgcn_mfma_f32_16x16x32_bf16(a, b, c, 0, 0, 0);
}

__device__ __forceinline__ void gload_lds16(const void* g, void* l) {
    __builtin_amdgcn_global_load_lds(
        (const __attribute__((address_space(1))) unsigned int*)(unsigned long long)g,
        (__attribute__((address_space(3))) unsigned int*)(unsigned int)(unsigned long long)l,
        16, 0, 0);
}

__device__ __forceinline__ unsigned pkbf(float a, float b) {
    unsigned short ua = __builtin_bit_cast(unsigned short, (__bf16)a);
    unsigned short ub = __builtin_bit_cast(unsigned short, (__bf16)b);
    return (unsigned)ua | ((unsigned)ub << 16);
}

__global__ void init_flag(int* flag) { *flag = 0; }

// f32 data read as bf16 halfwords shows huge exponents (p~0.45 per halfword).
__global__ void detect_f32(const unsigned short* __restrict__ w, int n, int* flag) {
    int i = blockIdx.x * blockDim.x + threadIdx.x;
    int hit = 0;
    for (; i < n; i += gridDim.x * blockDim.x) {
        int e = (w[i] >> 7) & 0xFF;
        if (e >= 0x8D) hit = 1;
    }
    unsigned long long m = __ballot(hit);
    if (m != 0 && (threadIdx.x & 63) == 0) atomicOr(flag, 1);
}

// Single launch: converts all three inputs f32->bf16 iff flag set; else no-op.
__global__ void cvt_all(const void* __restrict__ x, const void* __restrict__ wi,
                        const void* __restrict__ wo, __bf16* __restrict__ xb,
                        __bf16* __restrict__ wib, __bf16* __restrict__ wob,
                        const int* __restrict__ flag) {
    if (*flag == 0) return;
    const int XN = 8192 * 1024, WI = 3072 * 1024, WO = 1024 * 1024;
    const int stride = gridDim.x * blockDim.x;
    int i0 = blockIdx.x * blockDim.x + threadIdx.x;
    for (int j = i0; j < XN; j += stride) xb[j] = (__bf16)((const float*)x)[j];
    for (int j = i0; j < WI; j += stride) wib[j] = (__bf16)((const float*)wi)[j];
    for (int j = i0; j < WO; j += stride) wob[j] = (__bf16)((const float*)wo)[j];
}

// C[M,N] = A[M,K] @ Bt[N,K]^T. 128x128 tile, BK=64 (half the barriers of m97's
// BK=32), global_load_lds staging with XOR-chunk lane mapping: lane's GLOBAL
// chunk is permuted so the fixed lane*16 LDS layout lands swizzled ->
// ds_read_b128 conflicts stay at m97 levels despite pitch-64 rows.
__global__ __launch_bounds__(256, 3) void gemm_bt(
        const void* __restrict__ Araw, const __bf16* __restrict__ Acvt,
        const void* __restrict__ Braw, const __bf16* __restrict__ Bcvt,
        __bf16* __restrict__ Cb, float* __restrict__ Cf,
        const int* __restrict__ flagp, int M, int N, int K) {
    __shared__ __align__(16) __bf16 As[128 * 64];
    __shared__ __align__(16) __bf16 Bs[128 * 64];

    const int t = threadIdx.x;
    const int lane = t & 63;
    const int w = t >> 6;
    const int wr = w >> 1, wc = w & 1;
    const int q4 = lane >> 4, l16 = lane & 15;
    const int m0 = blockIdx.y * 128, n0 = blockIdx.x * 128;
    const bool isf32 = (*flagp != 0);
    const __bf16* A = isf32 ? Acvt : (const __bf16*)Araw;
    const __bf16* Bt = isf32 ? Bcvt : (const __bf16*)Braw;

    f32x4 acc[4][4] = {};

    // staging: instruction p of wave w covers rows w*32+p*8 .. +8 (8 rows x 128 B).
    // lane -> (row-in-8, global chunk): chunk = (lane&7) ^ (row&7) so that LDS
    // slot (row*8 + lane&7) holds global chunk (lane&7)^(row&7)  [row&7 == lr].
    const int lr = lane >> 3;
    const int lc = (lane & 7) ^ lr;

    for (int k0 = 0; k0 < K; k0 += 64) {
#pragma unroll
        for (int p = 0; p < 4; ++p) {
            int r0 = w * 32 + p * 8;
            gload_lds16(&A[(size_t)(m0 + r0 + lr) * K + k0 + lc * 8], &As[r0 * 64]);
            gload_lds16(&Bt[(size_t)(n0 + r0 + lr) * K + k0 + lc * 8], &Bs[r0 * 64]);
        }
        __syncthreads();

#pragma unroll
        for (int kt = 0; kt < 2; ++kt) {
            bf16x8 af[4], bfr[4];
#pragma unroll
            for (int mt = 0; mt < 4; ++mt) {
                int row = wr * 64 + mt * 16 + l16;
                af[mt] = *(const bf16x8*)&As[row * 64 + (((kt * 4 + q4) ^ (row & 7)) << 3)];
            }
#pragma unroll
            for (int nt = 0; nt < 4; ++nt) {
                int row = wc * 64 + nt * 16 + l16;
                bfr[nt] = *(const bf16x8*)&Bs[row * 64 + (((kt * 4 + q4) ^ (row & 7)) << 3)];
            }
#pragma unroll
            for (int mt = 0; mt < 4; ++mt)
#pragma unroll
                for (int nt = 0; nt < 4; ++nt)
                    acc[mt][nt] = mfma16(af[mt], bfr[nt], acc[mt][nt]);
        }
        __syncthreads();
    }

    // C/D layout: col=lane&15, row=(lane>>4)*4+reg
#pragma unroll
    for (int mt = 0; mt < 4; ++mt)
#pragma unroll
        for (int nt = 0; nt < 4; ++nt) {
            int col = n0 + wc * 64 + nt * 16 + l16;
#pragma unroll
            for (int r = 0; r < 4; ++r) {
                int row = m0 + wr * 64 + mt * 16 + q4 * 4 + r;
                if (Cf && isf32)
                    Cf[(size_t)row * N + col] = acc[mt][nt][r];
                else
                    Cb[(size_t)row * N + col] = (__bf16)acc[mt][nt][r];
            }
        }
}

// Sliding-window causal attention + ALiBi, flash-style, S^T orientation,
// 64-key sub-iterations, register-prefetched K/V staging, swizzled LDS.
// grid = (S/128, H, B), block = 256 (wave w owns queries [w*32, w*32+32)).
// (256,2): R5 showed (256,3)'s ~170-reg cap spills kpre/vpre (150 MB scratch).
// hh loop is unroll-1: unrolling doubled live sc[] ranges -> residual spill
// (R6: 48 MB scratch writes still visible in WRITE_SIZE).
__global__ __launch_bounds__(256, 2) void attn(
        const __bf16* __restrict__ qkv, __bf16* __restrict__ o) {
    // Ks : 128 keys x 64 d, pitch 64, chunk-swizzled   [0, 16384)
    // Vts: 64 d x 128 keys, pitch 136, chunk-swizzled  [16384, 33792)
    // Ps : 128 q x 64 keys, pitch 72                   [33792, 52224)
    // Ot : epilogue transpose buffer, aliases Ks
    __shared__ __align__(16) char smem[52224];
    __bf16* Ks  = (__bf16*)smem;
    __bf16* Vts = (__bf16*)(smem + 16384);
    __bf16* Ps  = (__bf16*)(smem + 33792);
    __bf16* Ot  = (__bf16*)smem;

    const int qt = blockIdx.x, h = blockIdx.y, b = blockIdx.z;
    const int t = threadIdx.x;
    const int lane = t & 63, w = t >> 6;
    const int q4 = lane >> 4, l16 = lane & 15;
    const int q0 = qt * 128, qw0 = q0 + w * 32;

    const float L2E = 1.4426950408889634f;
    const float slope2 = exp2f(-(float)(h + 1) * 0.5f) * L2E;  // alibi slope * log2e
    const float scale2 = L2E * 0.125f;                         // log2e / sqrt(64)

    // staging coords: thread handles chunk (row = p*32+srow, d-block scb)
    const int srow = t >> 3, scb = t & 7;
    const int ksoff = (scb ^ (srow & 7)) << 3;  // K swizzle (row&7 == srow&7 for all p)

    // Q as B-operand (lane l16 = query, k = d), straight b128 from global
    bf16x8 qf[2][2];
    const size_t qbase = ((size_t)b * 2048 + q0) * 3072 + (size_t)h * 64;
#pragma unroll
    for (int nt = 0; nt < 2; ++nt)
#pragma unroll
        for (int kt = 0; kt < 2; ++kt)
            qf[nt][kt] = *(const bf16x8*)&qkv[qbase +
                (size_t)(w * 32 + nt * 16 + l16) * 3072 + kt * 32 + q4 * 8];

    f32x4 O[4][2] = {};  // O^T: [d-tile][q-tile], col l16=q, row q4*4+r=d
    float mrow[2] = {-1e30f, -1e30f}, lrow[2] = {0.0f, 0.0f};

    const int nkt = (qt < 4 ? qt : 4) + 1;
    const int ktile0 = qt - (nkt - 1);
    const size_t bh = (size_t)b * 2048 * 3072 + (size_t)h * 64;

    uint4 kpre[4], vpre[4];

    // prologue: load + commit tile 0
    {
        const size_t kb = bh + (size_t)(ktile0 * 128) * 3072 + 1024;
#pragma unroll
        for (int p = 0; p < 4; ++p)
            kpre[p] = *(const uint4*)&qkv[kb + (size_t)(p * 32 + srow) * 3072 + scb * 8];
#pragma unroll
        for (int p = 0; p < 4; ++p)
            vpre[p] = *(const uint4*)&qkv[kb + 1024 + (size_t)(p * 32 + srow) * 3072 + scb * 8];
#pragma unroll
        for (int p = 0; p < 4; ++p) {
            *(uint4*)&Ks[(p * 32 + srow) * 64 + ksoff] = kpre[p];
            const __bf16* ve = (const __bf16*)&vpre[p];
            int R = p * 4 + (srow >> 3);
#pragma unroll
            for (int j = 0; j < 8; ++j)
                Vts[(scb * 8 + j) * 136 + ((R ^ scb) << 3) + (srow & 7)] = ve[j];
        }
    }
    __syncthreads();

    for (int ki = 0; ki < nkt; ++ki) {
        const int k0 = (ktile0 + ki) * 128;
        if (ki + 1 < nkt) {  // issue next tile's loads (no wait)
            const size_t kb = bh + (size_t)(k0 + 128) * 3072 + 1024;
#pragma unroll
            for (int p = 0; p < 4; ++p)
                kpre[p] = *(const uint4*)&qkv[kb + (size_t)(p * 32 + srow) * 3072 + scb * 8];
#pragma unroll
            for (int p = 0; p < 4; ++p)
                vpre[p] = *(const uint4*)&qkv[kb + 1024 + (size_t)(p * 32 + srow) * 3072 + scb * 8];
        }

#pragma unroll 1
        for (int hh = 0; hh < 2; ++hh) {
            const int ks0 = k0 + hh * 64;
            if (qw0 + 31 < ks0 || qw0 - 512 > ks0 + 63) continue;  // wave-uniform skip

            // S^T = K·Q^T over this 64-key subtile
            f32x4 sc[2][4] = {};
#pragma unroll
            for (int mt = 0; mt < 4; ++mt) {
                int krow = hh * 64 + mt * 16 + l16;
                bf16x8 ak0 = *(const bf16x8*)&Ks[krow * 64 + ((q4 ^ (l16 & 7)) << 3)];
                bf16x8 ak1 = *(const bf16x8*)&Ks[krow * 64 + (((4 + q4) ^ (l16 & 7)) << 3)];
                sc[0][mt] = mfma16(ak0, qf[0][0], sc[0][mt]);
                sc[0][mt] = mfma16(ak1, qf[0][1], sc[0][mt]);
                sc[1][mt] = mfma16(ak0, qf[1][0], sc[1][mt]);
                sc[1][mt] = mfma16(ak1, qf[1][1], sc[1][mt]);
            }

            // mask + bias + online-softmax update (per-lane state, query = l16)
            float al[2];
#pragma unroll
            for (int nt = 0; nt < 2; ++nt) {
                const int qi = qw0 + nt * 16 + l16;
                const int db = qi - ks0 - q4 * 4;  // delta = db - mt*16 - r
                float tmx = -1e30f;
#pragma unroll
                for (int mt = 0; mt < 4; ++mt)
#pragma unroll
                    for (int r = 0; r < 4; ++r) {
                        int delta = db - mt * 16 - r;
                        float v = sc[nt][mt][r] * scale2 + slope2 * (float)delta;
                        v = ((unsigned)delta <= 512u) ? v : -1e30f;
                        sc[nt][mt][r] = v;
                        tmx = fmaxf(tmx, v);
                    }
                tmx = fmaxf(tmx, __shfl_xor(tmx, 16));
                tmx = fmaxf(tmx, __shfl_xor(tmx, 32));
                float mnew = fmaxf(mrow[nt], tmx);
                al[nt] = exp2f(mrow[nt] - mnew);
                mrow[nt] = mnew;
#pragma unroll
                for (int mtd = 0; mtd < 4; ++mtd)
                    O[mtd][nt] *= al[nt];
            }

            // P (packed b64 writes into own 32-row strip) + row-sum
            float rsum[2] = {0.0f, 0.0f};
#pragma unroll
            for (int nt = 0; nt < 2; ++nt) {
                int qrow = w * 32 + nt * 16 + l16;
#pragma unroll
                for (int mt = 0; mt < 4; ++mt) {
                    float p0 = exp2f(sc[nt][mt][0] - mrow[nt]);
                    float p1 = exp2f(sc[nt][mt][1] - mrow[nt]);
                    float p2 = exp2f(sc[nt][mt][2] - mrow[nt]);
                    float p3 = exp2f(sc[nt][mt][3] - mrow[nt]);
                    rsum[nt] += (p0 + p1) + (p2 + p3);
                    uint2 pk;
                    pk.x = pkbf(p0, p1);
                    pk.y = pkbf(p2, p3);
                    *(uint2*)&Ps[qrow * 72 + mt * 16 + q4 * 4] = pk;
                }
            }

            // PV: A = V^T (swizzled Vts), B = P^T (same-wave Ps strip; in-order DS)
#pragma unroll
            for (int kt = 0; kt < 2; ++kt) {
                bf16x8 bp0 = *(const bf16x8*)&Ps[(w * 32 + l16) * 72 + kt * 32 + q4 * 8];
                bf16x8 bp1 = *(const bf16x8*)&Ps[(w * 32 + 16 + l16) * 72 + kt * 32 + q4 * 8];
#pragma unroll
                for (int mtd = 0; mtd < 4; ++mtd) {
                    int d = mtd * 16 + l16;
                    int kb2 = (hh * 8 + kt * 4 + q4) ^ ((mtd * 2 + (l16 >> 3)) & 7);
                    bf16x8 av = *(const bf16x8*)&Vts[d * 136 + (kb2 << 3)];
                    O[mtd][0] = mfma16(av, bp0, O[mtd][0]);
                    O[mtd][1] = mfma16(av, bp1, O[mtd][1]);
                }
            }
#pragma unroll
            for (int nt = 0; nt < 2; ++nt) {
                float rs = rsum[nt];
                rs += __shfl_xor(rs, 16);
                rs += __shfl_xor(rs, 32);
                lrow[nt] = lrow[nt] * al[nt] + rs;
            }
        }

        __syncthreads();  // all waves done reading Ks/Vts
        if (ki + 1 < nkt) {
#pragma unroll
            for (int p = 0; p < 4; ++p) {
                *(uint4*)&Ks[(p * 32 + srow) * 64 + ksoff] = kpre[p];
                const __bf16* ve = (const __bf16*)&vpre[p];
                int R = p * 4 + (srow >> 3);
#pragma unroll
                for (int j = 0; j < 8; ++j)
                    Vts[(scb * 8 + j) * 136 + ((R ^ scb) << 3) + (srow & 7)] = ve[j];
            }
        }
        __syncthreads();  // commits visible
    }

    // epilogue: normalize, transpose O^T -> O via swizzled Ot (aliases Ks; all
    // accesses stay within this wave's 32-query strip -> no barrier needed)
#pragma unroll
    for (int nt = 0; nt < 2; ++nt) {
        float inv = (lrow[nt] > 0.0f) ? 1.0f / lrow[nt] : 0.0f;
        int qrow = w * 32 + nt * 16 + l16;
#pragma unroll
        for (int mtd = 0; mtd < 4; ++mtd) {
            int chunk = (mtd * 2 + (q4 >> 1)) ^ (l16 & 7);
            uint2 pk;
            pk.x = pkbf(O[mtd][nt][0] * inv, O[mtd][nt][1] * inv);
            pk.y = pkbf(O[mtd][nt][2] * inv, O[mtd][nt][3] * inv);
            *(uint2*)&Ot[qrow * 64 + (chunk << 3) + (q4 & 1) * 4] = pk;
        }
    }
    const size_t obase = ((size_t)b * 2048 + q0) * 1024 + (size_t)h * 64;
#pragma unroll
    for (int i = 0; i < 4; ++i) {
        int u = i * 64 + lane;
        int row = u >> 3, ch = u & 7;
        int q = w * 32 + row;
        *(uint4*)&o[obase + (size_t)q * 1024 + ch * 8] =
            *(const uint4*)&Ot[q * 64 + ((ch ^ (row & 7)) << 3)];
    }
}

extern "C" void kernel_launch(void* const* d_in, const int* in_sizes, int n_in,
                              void* d_out, int out_size, void* d_ws, size_t ws_size,
                              hipStream_t stream) {
    char* ws = (char*)d_ws;
    int* flag = (int*)ws;
    size_t off = 256;
    __bf16* xb  = (__bf16*)(ws + off); off += (size_t)8192 * 1024 * 2;
    __bf16* wib = (__bf16*)(ws + off); off += (size_t)3072 * 1024 * 2;
    __bf16* wob = (__bf16*)(ws + off); off += (size_t)1024 * 1024 * 2;
    __bf16* qkv = (__bf16*)(ws + off); off += (size_t)8192 * 3072 * 2;
    __bf16* o   = (__bf16*)(ws + off);

    init_flag<<<1, 1, 0, stream>>>(flag);
    int nscan = in_sizes[2] < 65536 ? in_sizes[2] : 65536;
    detect_f32<<<16, 256, 0, stream>>>((const unsigned short*)d_in[2], nscan, flag);
    cvt_all<<<1024, 256, 0, stream>>>(d_in[0], d_in[1], d_in[2], xb, wib, wob, flag);

    // qkv = x @ w_in^T
    gemm_bt<<<dim3(24, 64), 256, 0, stream>>>(d_in[0], xb, d_in[1], wib,
                                              qkv, nullptr, flag, 8192, 3072, 1024);
    // attention
    attn<<<dim3(16, 16, 4), 256, 0, stream>>>(qkv, o);
    // out = o @ w_out^T (output dtype per flag)
    gemm_bt<<<dim3(8, 64), 256, 0, stream>>>(o, o, d_in[2], wob,
                                             (__bf16*)d_out, (float*)d_out, flag,
                                             8192, 1024, 1024);
}